// Round 5
// baseline (780.632 us; speedup 1.0000x reference)
//
#include <hip/hip_runtime.h>
#include <math.h>

#define NTOK 4096   // B*T = 2*2048
#define DM   1024
#define DH   4096
#define NE   8
#define NSLOT (NTOK*2)
#define TM   40     // max compacted (expert, mb) 256-row tiles: sum ceil(cnt_e/256) <= 32+8

typedef unsigned short u16;
typedef __attribute__((ext_vector_type(8))) short shortx8;  // 8 bf16
typedef __attribute__((ext_vector_type(4))) float floatx4;
typedef __attribute__((ext_vector_type(4))) int   intx4;

__device__ __forceinline__ u16 f2bf(float f) {
  union { float f; unsigned u; } c; c.f = f;
  unsigned r = c.u + 0x7fffu + ((c.u >> 16) & 1u);   // RNE
  return (u16)(r >> 16);
}

// async 16B/lane global -> LDS (dest = wave-uniform base + lane*16)
__device__ __forceinline__ void async_cp16(const u16* g, u16* l) {
  __builtin_amdgcn_global_load_lds(
      (const __attribute__((address_space(1))) void*)g,
      (__attribute__((address_space(3))) void*)l, 16, 0, 0);
}

// ---------------- x -> bf16 ----------------
__global__ void cvt_x_kernel(const float* __restrict__ x, u16* __restrict__ xb) {
  int i = (blockIdx.x * 256 + threadIdx.x) * 8;
  float4 v0 = *(const float4*)(x + i);
  float4 v1 = *(const float4*)(x + i + 4);
  u16 tmp[8] = {f2bf(v0.x), f2bf(v0.y), f2bf(v0.z), f2bf(v0.w),
                f2bf(v1.x), f2bf(v1.y), f2bf(v1.z), f2bf(v1.w)};
  *(intx4*)(xb + i) = *(intx4*)tmp;
}

// ---------------- W [E][K][NW] fp32 -> Wt [E][NW][K] bf16, LDS-tiled ----------------
template<int K, int NW>
__global__ __launch_bounds__(256) void transpose_kernel(const float* __restrict__ W,
                                                        u16* __restrict__ Wt) {
  __shared__ u16 tile[64][66];   // stride 66 u16 = 132 B
  int e = blockIdx.z;
  int n0 = blockIdx.x * 64, k0 = blockIdx.y * 64;
  int tt = threadIdx.x;
  const float* src = W + (size_t)e * K * NW + (size_t)(k0 + (tt >> 2)) * NW + n0 + (tt & 3) * 16;
  int r = tt >> 2, c4 = (tt & 3) * 16;
  float4 v[4];
#pragma unroll
  for (int i = 0; i < 4; i++) v[i] = *(const float4*)(src + i * 4);
#pragma unroll
  for (int i = 0; i < 4; i++) {
    tile[r][c4 + 4 * i + 0] = f2bf(v[i].x);
    tile[r][c4 + 4 * i + 1] = f2bf(v[i].y);
    tile[r][c4 + 4 * i + 2] = f2bf(v[i].z);
    tile[r][c4 + 4 * i + 3] = f2bf(v[i].w);
  }
  __syncthreads();
  u16* dst = Wt + (size_t)e * NW * K + (size_t)n0 * K + k0;
#pragma unroll
  for (int p = 0; p < 2; p++) {
    int n = (tt >> 3) + p * 32;
    int kc = (tt & 7) * 8;
    u16 o[8];
#pragma unroll
    for (int i = 0; i < 8; i++) o[i] = tile[kc + i][n];
    *(intx4*)(dst + (size_t)n * K + kc) = *(intx4*)o;
  }
}

// ---------------- router ----------------
__global__ __launch_bounds__(256) void router_kernel(const float* __restrict__ x,
                                                     const float* __restrict__ gw,
                                                     int* __restrict__ eos,
                                                     float* __restrict__ wos) {
  int wave = threadIdx.x >> 6, lane = threadIdx.x & 63;
  int n = blockIdx.x * 4 + wave;
  const float* xr = x + (size_t)n * DM;
  float acc[NE];
#pragma unroll
  for (int e = 0; e < NE; e++) acc[e] = 0.f;
  for (int d = lane; d < DM; d += 64) {
    float xv = xr[d];
#pragma unroll
    for (int e = 0; e < NE; e++) acc[e] += xv * gw[e * DM + d];
  }
#pragma unroll
  for (int e = 0; e < NE; e++) {
    float v = acc[e];
#pragma unroll
    for (int off = 32; off > 0; off >>= 1) v += __shfl_xor(v, off, 64);
    acc[e] = v;
  }
  if (lane == 0) {
    int i0 = 0;
    for (int e = 1; e < NE; e++) if (acc[e] > acc[i0]) i0 = e;
    int i1 = (i0 == 0) ? 1 : 0;
    for (int e = 0; e < NE; e++) { if (e == i0) continue; if (acc[e] > acc[i1]) i1 = e; }
    float e1 = expf(acc[i1] - acc[i0]);
    float w0 = 1.f / (1.f + e1);
    eos[2 * n] = i0;  eos[2 * n + 1] = i1;
    wos[2 * n] = w0;  wos[2 * n + 1] = 1.f - w0;
  }
}

// ---------------- counting sort + compacted tile list (256-row tiles) ----------------
__global__ __launch_bounds__(256) void build_groups_kernel(
    const int* __restrict__ eos, const float* __restrict__ wos,
    int* __restrict__ goff, int* __restrict__ tok_of_g, float* __restrict__ w_of_g,
    int* __restrict__ tiles, int* __restrict__ ntiles) {
  __shared__ int pref[256][NE];
  __shared__ int tot[NE];
  __shared__ int ebase[NE + 1];
  int t = threadIdx.x;
  int c[NE];
#pragma unroll
  for (int e = 0; e < NE; e++) c[e] = 0;
  for (int i = 0; i < NSLOT / 256; i++) {
    int e = eos[t * (NSLOT / 256) + i];
#pragma unroll
    for (int q = 0; q < NE; q++) if (e == q) c[q]++;
  }
#pragma unroll
  for (int e = 0; e < NE; e++) pref[t][e] = c[e];
  __syncthreads();
  if (t < NE) {
    int run = 0;
    for (int i = 0; i < 256; i++) { int v = pref[i][t]; pref[i][t] = run; run += v; }
    tot[t] = run;
  }
  __syncthreads();
  if (t == 0) {
    int o = 0;
    for (int e = 0; e < NE; e++) { ebase[e] = o; o += tot[e]; }
    ebase[NE] = o;
    int nt = 0;
    for (int e = 0; e < NE; e++)
      for (int mb = 0; mb * 256 < tot[e]; mb++) tiles[nt++] = (e << 16) | mb;
    ntiles[0] = nt;
  }
  __syncthreads();
  int off[NE];
#pragma unroll
  for (int e = 0; e < NE; e++) off[e] = ebase[e] + pref[t][e];
  for (int i = 0; i < NSLOT / 256; i++) {
    int s = t * (NSLOT / 256) + i;
    int e = eos[s];
    int g = 0;
#pragma unroll
    for (int q = 0; q < NE; q++) if (e == q) { g = off[q]; off[q] = g + 1; }
    tok_of_g[g] = s >> 1;
    w_of_g[g] = wos[s];
  }
  if (t <= NE) goff[t] = ebase[t];
}

// ---------------- grouped GEMM: 256x256 tile, BK=64, counted-vmcnt ----------
// Round-4 post-mortem: staged bytes per MFMA (256B at 128x128) is the binding
// constraint (L1/VMEM path ~64B/cy/CU -> ~1000cy/K-step vs 310cy MFMA); all
// schedule variants pinned at 12-14% MfmaUtil. 256x256 tile halves bytes/MFMA
// to 128B. 512 thr = 8 waves (2M x 4N), per-wave 128x64 out = acc[8][4].
// LDS 128KB (guide m201 geometry), 1 block/CU. Sync skeleton = round-4 proven:
// vmcnt(8) counted across barriers, stage-after-read-barrier, swizzle both-sides.
// Sequential k-halves (12 ds_read + 32 MFMA each) to stay under 256 VGPR.
template<int K, int NOUT, int MODE, int KSPLIT>
__global__ __launch_bounds__(512, 2) void moe_gemm(
    const u16* __restrict__ A, const u16* __restrict__ Wt, const float* __restrict__ bias,
    const int* __restrict__ goff, const int* __restrict__ tok_of_g,
    const float* __restrict__ w_of_g, const int* __restrict__ tiles,
    const int* __restrict__ ntiles,
    u16* __restrict__ Hout, float* __restrict__ Out) {
  const int KLEN = K / KSPLIT;
  const int NB = NOUT / 256;
  const int NWG = TM * NB * KSPLIT;            // 640 / 640 -- %8==0
  int flat = blockIdx.x;
  int wgid = (flat & 7) * (NWG >> 3) + (flat >> 3);   // XCD-contiguous chunks
  int nb   = wgid % NB;
  int rest = wgid / NB;
  int tl   = rest % TM;
  int kseg = rest / TM;
  if (tl >= ntiles[0]) return;
  int packed = tiles[tl];
  int e = packed >> 16;
  int mb = packed & 0xffff;
  int gb = goff[e];
  int cntE = goff[e + 1] - gb;
  int m0 = mb * 256;
  int mvalid = cntE - m0; if (mvalid > 256) mvalid = 256;
  int gbase = gb + m0;
  int n0 = nb * 256;
  int kbeg = kseg * KLEN;
  int tid = threadIdx.x;
  int lane = tid & 63, wave = tid >> 6;

  __shared__ __align__(16) u16 As[2][256 * 64];   // 2 x 32 KB
  __shared__ __align__(16) u16 Bs[2][256 * 64];   // total 128 KB

  // staging: wave w stages rows [w*32, w*32+32) of A and B; each async_cp16
  // covers 8 rows (64 lanes x 16B). lane -> row += lane>>3, chunk = lane&7.
  // Global column pre-swizzled: chunk ^ (row&7) = (lane&7) ^ (lane>>3).
  int gcol = (((lane & 7) ^ (lane >> 3)) * 8);
  const u16 *pA[4], *pB[4];
  const u16* wte = Wt + (size_t)e * NOUT * K;
#pragma unroll
  for (int i = 0; i < 4; i++) {
    int rw = wave * 32 + i * 8 + (lane >> 3);
    int cw = (rw < mvalid) ? rw : (mvalid - 1);
    if (MODE == 0) pA[i] = A + (size_t)tok_of_g[gbase + cw] * K + gcol;
    else           pA[i] = A + (size_t)(gbase + cw) * K + gcol;
    pB[i] = wte + (size_t)(n0 + rw) * K + gcol;
  }

  int wm = wave >> 2, wn = wave & 3;   // 2M x 4N wave grid
  int lr = lane & 15;
  // read-side swizzled cols (u16) for k-half h: chunk = (h*4 + lane>>4) ^ (lr&7)
  int c0 = (((lane >> 4)) ^ (lr & 7)) * 8;
  int c1 = ((4 + (lane >> 4)) ^ (lr & 7)) * 8;

  floatx4 acc[8][4];
#pragma unroll
  for (int i = 0; i < 8; i++)
#pragma unroll
    for (int j = 0; j < 4; j++) acc[i][j] = (floatx4){0.f, 0.f, 0.f, 0.f};

  auto stage = [&](int b, int k0) {
#pragma unroll
    for (int i = 0; i < 4; i++)
      async_cp16(pA[i] + k0, &As[b][(wave * 32 + i * 8) * 64]);
#pragma unroll
    for (int i = 0; i < 4; i++)
      async_cp16(pB[i] + k0, &Bs[b][(wave * 32 + i * 8) * 64]);
  };

  const int NT = KLEN / 64;   // 16 for both GEMMs
  stage(0, kbeg);
  stage(1, kbeg + 64);

  shortx8 af[8], bfr[4];
  auto ldfrag_half = [&](int b, int h) {
    int cc = h ? c1 : c0;
#pragma unroll
    for (int i = 0; i < 8; i++)
      af[i]  = *(const shortx8*)&As[b][(wm * 128 + i * 16 + lr) * 64 + cc];
#pragma unroll
    for (int j = 0; j < 4; j++)
      bfr[j] = *(const shortx8*)&Bs[b][(wn * 64 + j * 16 + lr) * 64 + cc];
  };
  auto mfma_half = [&]() {
#pragma unroll
    for (int i = 0; i < 8; i++)
#pragma unroll
      for (int j = 0; j < 4; j++)
        acc[i][j] = __builtin_amdgcn_mfma_f32_16x16x32_bf16(af[i], bfr[j], acc[i][j], 0, 0, 0);
  };

  for (int t = 0; t < NT - 2; ++t) {
    int cur = t & 1;
    asm volatile("s_waitcnt vmcnt(8)" ::: "memory");   // cur buf complete; next's 8 in flight
    __builtin_amdgcn_s_barrier();
    asm volatile("" ::: "memory");
    ldfrag_half(cur, 0);
    asm volatile("s_waitcnt lgkmcnt(0)" ::: "memory");
    __builtin_amdgcn_sched_barrier(0);
    __builtin_amdgcn_s_setprio(1);
    mfma_half();
    __builtin_amdgcn_s_setprio(0);
    ldfrag_half(cur, 1);
    asm volatile("s_waitcnt lgkmcnt(0)" ::: "memory");
    __builtin_amdgcn_sched_barrier(0);
    __builtin_amdgcn_s_barrier();                      // all waves done reading cur
    __builtin_amdgcn_sched_barrier(0);
    stage(cur, kbeg + (t + 2) * 64);                   // overwrite cur with t+2
    __builtin_amdgcn_sched_barrier(0);
    __builtin_amdgcn_s_setprio(1);
    mfma_half();
    __builtin_amdgcn_s_setprio(0);
  }
#pragma unroll
  for (int tt2 = 0; tt2 < 2; ++tt2) {   // tails: t = NT-2 (wait 8), t = NT-1 (wait 0)
    int cur = (NT + tt2) & 1;
    if (tt2 == 0) asm volatile("s_waitcnt vmcnt(8)" ::: "memory");
    else          asm volatile("s_waitcnt vmcnt(0)" ::: "memory");
    __builtin_amdgcn_s_barrier();
    asm volatile("" ::: "memory");
    ldfrag_half(cur, 0);
    asm volatile("s_waitcnt lgkmcnt(0)" ::: "memory");
    __builtin_amdgcn_sched_barrier(0);
    mfma_half();
    ldfrag_half(cur, 1);
    asm volatile("s_waitcnt lgkmcnt(0)" ::: "memory");
    __builtin_amdgcn_sched_barrier(0);
    mfma_half();
  }

  const float* bp = bias + (size_t)e * NOUT + n0;
  if (MODE == 0) {
#pragma unroll
    for (int i = 0; i < 8; i++) {
      int rowb = wm * 128 + i * 16 + (lane >> 4) * 4;
#pragma unroll
      for (int r = 0; r < 4; r++) {
        int grow = rowb + r;
        if (grow < mvalid) {
          size_t base = (size_t)(gbase + grow) * NOUT + n0;
#pragma unroll
          for (int j = 0; j < 4; j++) {
            int col = wn * 64 + j * 16 + lr;
            float v = acc[i][j][r] + bp[col];
            v = 0.5f * v * (1.f + erff(v * 0.70710678118654752f));  // exact gelu
            Hout[base + col] = f2bf(v);
          }
        }
      }
    }
  } else {
#pragma unroll
    for (int i = 0; i < 8; i++) {
      int rowb = wm * 128 + i * 16 + (lane >> 4) * 4;
#pragma unroll
      for (int r = 0; r < 4; r++) {
        int grow = rowb + r;
        if (grow < mvalid) {
          int gi = gbase + grow;
          int t = tok_of_g[gi];
          float wg = w_of_g[gi];
          float* orow = Out + (size_t)t * DM + n0;
#pragma unroll
          for (int j = 0; j < 4; j++) {
            int col = wn * 64 + j * 16 + lr;
            float bb = (kseg == 0) ? bp[col] : 0.f;
            atomicAdd(&orow[col], wg * (acc[i][j][r] + bb));
          }
        }
      }
    }
  }
}

extern "C" void kernel_launch(void* const* d_in, const int* in_sizes, int n_in,
                              void* d_out, int out_size, void* d_ws, size_t ws_size,
                              hipStream_t stream) {
  const float* x  = (const float*)d_in[0];
  const float* gw = (const float*)d_in[1];
  const float* w1 = (const float*)d_in[2];
  const float* b1 = (const float*)d_in[3];
  const float* w2 = (const float*)d_in[4];
  const float* b2 = (const float*)d_in[5];
  float* out = (float*)d_out;
  char* ws = (char*)d_ws;

  u16* xb = (u16*)(ws + 0);                       // 8 MB
  u16* wt = (u16*)(ws + 8388608);                 // 64 MB (w1t, then w2t)
  u16* h  = (u16*)(ws + 75497472);                // 64 MB
  char* meta = ws + 142606336;
  int*   eos      = (int*)(meta);
  int*   tok_of_g = (int*)(meta + 32768);
  float* wos      = (float*)(meta + 65536);
  float* w_of_g   = (float*)(meta + 98304);
  int*   goff     = (int*)(meta + 131072);
  int*   tiles    = (int*)(meta + 131200);
  int*   ntiles   = (int*)(meta + 131584);

  hipMemsetAsync(out, 0, (size_t)NTOK * DM * 4, stream);

  cvt_x_kernel<<<NTOK * DM / 8 / 256, 256, 0, stream>>>(x, xb);
  transpose_kernel<DM, DH><<<dim3(DH / 64, DM / 64, NE), 256, 0, stream>>>(w1, wt);
  router_kernel<<<NTOK / 4, 256, 0, stream>>>(x, gw, eos, wos);
  build_groups_kernel<<<1, 256, 0, stream>>>(eos, wos, goff, tok_of_g, w_of_g, tiles, ntiles);
  // GEMM1: 256x256 tiles, 1D grid, XCD-chunk swizzled inside kernel
  moe_gemm<DM, DH, 0, 1><<<TM * (DH / 256), 512, 0, stream>>>(
      xb, wt, b1, goff, tok_of_g, w_of_g, tiles, ntiles, h, nullptr);
  transpose_kernel<DH, DM><<<dim3(DM / 64, DH / 64, NE), 256, 0, stream>>>(w2, wt);
  // GEMM2: 256x256 tiles, split-K x4 (KLEN=1024, NT=16; grid 640)
  moe_gemm<DH, DM, 1, 4><<<TM * (DM / 256) * 4, 512, 0, stream>>>(
      h, wt, b2, goff, tok_of_g, w_of_g, tiles, ntiles, nullptr, out);
}

// Round 6
// 655.505 us; speedup vs baseline: 1.1909x; 1.1909x over previous
//
#include <hip/hip_runtime.h>
#include <math.h>

#define NTOK 4096   // B*T = 2*2048
#define DM   1024
#define DH   4096
#define NE   8
#define NSLOT (NTOK*2)
#define TMAX 72     // max compacted (expert, mb) tiles: sum ceil(cnt_e/128) <= 64+7

typedef unsigned short u16;
typedef __attribute__((ext_vector_type(8))) short shortx8;  // 8 bf16
typedef __attribute__((ext_vector_type(4))) float floatx4;
typedef __attribute__((ext_vector_type(4))) int   intx4;

__device__ __forceinline__ u16 f2bf(float f) {
  union { float f; unsigned u; } c; c.f = f;
  unsigned r = c.u + 0x7fffu + ((c.u >> 16) & 1u);   // RNE
  return (u16)(r >> 16);
}

// async 16B/lane global -> LDS (dest = wave-uniform base + lane*16)
__device__ __forceinline__ void async_cp16(const u16* g, u16* l) {
  __builtin_amdgcn_global_load_lds(
      (const __attribute__((address_space(1))) void*)g,
      (__attribute__((address_space(3))) void*)l, 16, 0, 0);
}

// ---------------- x -> bf16 ----------------
__global__ void cvt_x_kernel(const float* __restrict__ x, u16* __restrict__ xb) {
  int i = (blockIdx.x * 256 + threadIdx.x) * 8;
  float4 v0 = *(const float4*)(x + i);
  float4 v1 = *(const float4*)(x + i + 4);
  u16 tmp[8] = {f2bf(v0.x), f2bf(v0.y), f2bf(v0.z), f2bf(v0.w),
                f2bf(v1.x), f2bf(v1.y), f2bf(v1.z), f2bf(v1.w)};
  *(intx4*)(xb + i) = *(intx4*)tmp;
}

// ---------------- W [E][K][NW] fp32 -> Wt [E][NW][K] bf16, LDS-tiled ----------------
template<int K, int NW>
__global__ __launch_bounds__(256) void transpose_kernel(const float* __restrict__ W,
                                                        u16* __restrict__ Wt) {
  __shared__ u16 tile[64][66];   // stride 66 u16 = 132 B
  int e = blockIdx.z;
  int n0 = blockIdx.x * 64, k0 = blockIdx.y * 64;
  int tt = threadIdx.x;
  const float* src = W + (size_t)e * K * NW + (size_t)(k0 + (tt >> 2)) * NW + n0 + (tt & 3) * 16;
  int r = tt >> 2, c4 = (tt & 3) * 16;
  float4 v[4];
#pragma unroll
  for (int i = 0; i < 4; i++) v[i] = *(const float4*)(src + i * 4);
#pragma unroll
  for (int i = 0; i < 4; i++) {
    tile[r][c4 + 4 * i + 0] = f2bf(v[i].x);
    tile[r][c4 + 4 * i + 1] = f2bf(v[i].y);
    tile[r][c4 + 4 * i + 2] = f2bf(v[i].z);
    tile[r][c4 + 4 * i + 3] = f2bf(v[i].w);
  }
  __syncthreads();
  u16* dst = Wt + (size_t)e * NW * K + (size_t)n0 * K + k0;
#pragma unroll
  for (int p = 0; p < 2; p++) {
    int n = (tt >> 3) + p * 32;
    int kc = (tt & 7) * 8;
    u16 o[8];
#pragma unroll
    for (int i = 0; i < 8; i++) o[i] = tile[kc + i][n];
    *(intx4*)(dst + (size_t)n * K + kc) = *(intx4*)o;
  }
}

// ---------------- router ----------------
__global__ __launch_bounds__(256) void router_kernel(const float* __restrict__ x,
                                                     const float* __restrict__ gw,
                                                     int* __restrict__ eos,
                                                     float* __restrict__ wos) {
  int wave = threadIdx.x >> 6, lane = threadIdx.x & 63;
  int n = blockIdx.x * 4 + wave;
  const float* xr = x + (size_t)n * DM;
  float acc[NE];
#pragma unroll
  for (int e = 0; e < NE; e++) acc[e] = 0.f;
  for (int d = lane; d < DM; d += 64) {
    float xv = xr[d];
#pragma unroll
    for (int e = 0; e < NE; e++) acc[e] += xv * gw[e * DM + d];
  }
#pragma unroll
  for (int e = 0; e < NE; e++) {
    float v = acc[e];
#pragma unroll
    for (int off = 32; off > 0; off >>= 1) v += __shfl_xor(v, off, 64);
    acc[e] = v;
  }
  if (lane == 0) {
    int i0 = 0;
    for (int e = 1; e < NE; e++) if (acc[e] > acc[i0]) i0 = e;
    int i1 = (i0 == 0) ? 1 : 0;
    for (int e = 0; e < NE; e++) { if (e == i0) continue; if (acc[e] > acc[i1]) i1 = e; }
    float e1 = expf(acc[i1] - acc[i0]);
    float w0 = 1.f / (1.f + e1);
    eos[2 * n] = i0;  eos[2 * n + 1] = i1;
    wos[2 * n] = w0;  wos[2 * n + 1] = 1.f - w0;
  }
}

// ---------------- counting sort + compacted tile list ----------------
__global__ __launch_bounds__(256) void build_groups_kernel(
    const int* __restrict__ eos, const float* __restrict__ wos,
    int* __restrict__ goff, int* __restrict__ tok_of_g, float* __restrict__ w_of_g,
    int* __restrict__ tiles, int* __restrict__ ntiles) {
  __shared__ int pref[256][NE];
  __shared__ int tot[NE];
  __shared__ int ebase[NE + 1];
  int t = threadIdx.x;
  int c[NE];
#pragma unroll
  for (int e = 0; e < NE; e++) c[e] = 0;
  for (int i = 0; i < NSLOT / 256; i++) {
    int e = eos[t * (NSLOT / 256) + i];
#pragma unroll
    for (int q = 0; q < NE; q++) if (e == q) c[q]++;
  }
#pragma unroll
  for (int e = 0; e < NE; e++) pref[t][e] = c[e];
  __syncthreads();
  if (t < NE) {
    int run = 0;
    for (int i = 0; i < 256; i++) { int v = pref[i][t]; pref[i][t] = run; run += v; }
    tot[t] = run;
  }
  __syncthreads();
  if (t == 0) {
    int o = 0;
    for (int e = 0; e < NE; e++) { ebase[e] = o; o += tot[e]; }
    ebase[NE] = o;
    int nt = 0;
    for (int e = 0; e < NE; e++)
      for (int mb = 0; mb * 128 < tot[e]; mb++) tiles[nt++] = (e << 16) | mb;
    ntiles[0] = nt;
  }
  __syncthreads();
  int off[NE];
#pragma unroll
  for (int e = 0; e < NE; e++) off[e] = ebase[e] + pref[t][e];
  for (int i = 0; i < NSLOT / 256; i++) {
    int s = t * (NSLOT / 256) + i;
    int e = eos[s];
    int g = 0;
#pragma unroll
    for (int q = 0; q < NE; q++) if (e == q) { g = off[q]; off[q] = g + 1; }
    tok_of_g[g] = s >> 1;
    w_of_g[g] = wos[s];
  }
  if (t <= NE) goff[t] = ebase[t];
}

// ---------------- grouped GEMM: R0 loop + occupancy & locality levers -----------
// Post-mortem R0-R5: MfmaUtil = 0.65 x Occupancy across ALL schedule variants ->
// wave-TLP-bound. Keep R0's single-buffered 16KB-LDS compiler-scheduled loop
// (best measured: 198us). Levers applied (no sync-structure change):
//  - __launch_bounds__(256,4): R0 was 76V+64A=140 regs -> 3 waves/SIMD; target
//    <=128 unified -> 4 waves/SIMD (16 waves/CU).
//  - T1 XCD-chunk remap + 4x4 supertile: 16 blocks share 4 A-tiles + 4 B-panels
//    (2MB, L2-fits) -> L2-miss stream ~4x down (B re-fetch was ~600MB/dispatch,
//    invisible in FETCH_SIZE which counts HBM only).
//  - T2 swizzle (R1 refcheck-proven): conflicts 8.8M -> 0.
// MODE 0: A=xb gathered rows -> gelu -> h (bf16)
// MODE 1: A=h contiguous rows -> gate-weighted atomicAdd -> out (fp32); bias kseg0 only
template<int K, int NOUT, int MODE, int KSPLIT>
__global__ __launch_bounds__(256, 4) void moe_gemm(
    const u16* __restrict__ A, const u16* __restrict__ Wt, const float* __restrict__ bias,
    const int* __restrict__ goff, const int* __restrict__ tok_of_g,
    const float* __restrict__ w_of_g, const int* __restrict__ tiles,
    const int* __restrict__ ntiles,
    u16* __restrict__ Hout, float* __restrict__ Out) {
  const int KLEN = K / KSPLIT;
  const int NB = NOUT / 128;      // 32 (G1) / 8 (G2)
  const int NBG = NB / 4;         // nb supertile-cols: 8 / 2
  const int NWG = TMAX * NB * KSPLIT;   // 2304 / 1152, both %8==0
  // XCD-contiguous chunks, then 4x4 (tile x nb) supertiles within the chunk.
  int flat = blockIdx.x;
  int wgid = (flat & 7) * (NWG >> 3) + (flat >> 3);
  int kseg = (KSPLIT > 1) ? (wgid / (TMAX * NB)) : 0;
  int r0w  = wgid % (TMAX * NB);
  int st = r0w >> 4, within = r0w & 15;
  int tl = (st / NBG) * 4 + (within >> 2);   // [0, TMAX)
  int nb = (st % NBG) * 4 + (within & 3);    // [0, NB)
  if (tl >= ntiles[0]) return;
  int packed = tiles[tl];
  int e = packed >> 16;
  int mb = packed & 0xffff;
  int gb = goff[e];
  int cntE = goff[e + 1] - gb;
  int m0 = mb * 128;
  int mvalid = cntE - m0; if (mvalid > 128) mvalid = 128;
  int gbase = gb + m0;
  int n0 = nb * 128;
  int kbeg = kseg * KLEN;
  int tid = threadIdx.x;
  int lane = tid & 63, wave = tid >> 6;

  __shared__ __align__(16) u16 As[128 * 32];   // 8 KB
  __shared__ __align__(16) u16 Bs[128 * 32];

  int sr = lane >> 2;
  int sc = (lane & 3) * 8;
  // stage-side swizzle (pre-swizzled GLOBAL source, linear LDS dest; R1-proven)
  int scs = sc ^ (((sr >> 1) & 3) << 3);
  int ra0 = wave * 16 + sr;
  int ra1 = 64 + wave * 16 + sr;
  int ca0 = (ra0 < mvalid) ? ra0 : (mvalid - 1);
  int ca1 = (ra1 < mvalid) ? ra1 : (mvalid - 1);
  const u16 *pa0, *pa1;
  if (MODE == 0) {
    pa0 = A + (size_t)tok_of_g[gbase + ca0] * K + scs;
    pa1 = A + (size_t)tok_of_g[gbase + ca1] * K + scs;
  } else {
    pa0 = A + (size_t)(gbase + ca0) * K + scs;
    pa1 = A + (size_t)(gbase + ca1) * K + scs;
  }
  const u16* wte = Wt + (size_t)e * NOUT * K;
  const u16* pb0 = wte + (size_t)(n0 + ra0) * K + scs;
  const u16* pb1 = wte + (size_t)(n0 + ra1) * K + scs;
  u16* ldsA0 = As + wave * 512;
  u16* ldsA1 = As + 2048 + wave * 512;
  u16* ldsB0 = Bs + wave * 512;
  u16* ldsB1 = Bs + 2048 + wave * 512;

  int wm = wave >> 1, wn = wave & 1;
  int lr = lane & 15, lk = (lane >> 4) * 8;
  int lks = lk ^ (((lr >> 1) & 3) << 3);   // read-side: same involution

  floatx4 acc[4][4];
#pragma unroll
  for (int i = 0; i < 4; i++)
#pragma unroll
    for (int j = 0; j < 4; j++) acc[i][j] = (floatx4){0.f, 0.f, 0.f, 0.f};

  for (int k0 = kbeg; k0 < kbeg + KLEN; k0 += 32) {
    __syncthreads();
    async_cp16(pa0 + k0, ldsA0);
    async_cp16(pa1 + k0, ldsA1);
    async_cp16(pb0 + k0, ldsB0);
    async_cp16(pb1 + k0, ldsB1);
    __syncthreads();
    shortx8 af[4], bfr[4];
#pragma unroll
    for (int i = 0; i < 4; i++) {
      af[i]  = *(const shortx8*)&As[(wm * 64 + i * 16 + lr) * 32 + lks];
      bfr[i] = *(const shortx8*)&Bs[(wn * 64 + i * 16 + lr) * 32 + lks];
    }
#pragma unroll
    for (int i = 0; i < 4; i++)
#pragma unroll
      for (int j = 0; j < 4; j++)
        acc[i][j] = __builtin_amdgcn_mfma_f32_16x16x32_bf16(af[i], bfr[j], acc[i][j], 0, 0, 0);
  }

  const float* bp = bias + (size_t)e * NOUT + n0;
  if (MODE == 0) {
#pragma unroll
    for (int i = 0; i < 4; i++) {
      int rowb = wm * 64 + i * 16 + (lane >> 4) * 4;
#pragma unroll
      for (int r = 0; r < 4; r++) {
        int grow = rowb + r;
        if (grow < mvalid) {
          size_t base = (size_t)(gbase + grow) * NOUT + n0;
#pragma unroll
          for (int j = 0; j < 4; j++) {
            int col = wn * 64 + j * 16 + lr;
            float v = acc[i][j][r] + bp[col];
            v = 0.5f * v * (1.f + erff(v * 0.70710678118654752f));  // exact gelu
            Hout[base + col] = f2bf(v);
          }
        }
      }
    }
  } else {
#pragma unroll
    for (int i = 0; i < 4; i++) {
      int rowb = wm * 64 + i * 16 + (lane >> 4) * 4;
#pragma unroll
      for (int r = 0; r < 4; r++) {
        int grow = rowb + r;
        if (grow < mvalid) {
          int gi = gbase + grow;
          int t = tok_of_g[gi];
          float wg = w_of_g[gi];
          float* orow = Out + (size_t)t * DM + n0;
#pragma unroll
          for (int j = 0; j < 4; j++) {
            int col = wn * 64 + j * 16 + lr;
            float bb = (kseg == 0) ? bp[col] : 0.f;
            atomicAdd(&orow[col], wg * (acc[i][j][r] + bb));
          }
        }
      }
    }
  }
}

extern "C" void kernel_launch(void* const* d_in, const int* in_sizes, int n_in,
                              void* d_out, int out_size, void* d_ws, size_t ws_size,
                              hipStream_t stream) {
  const float* x  = (const float*)d_in[0];
  const float* gw = (const float*)d_in[1];
  const float* w1 = (const float*)d_in[2];
  const float* b1 = (const float*)d_in[3];
  const float* w2 = (const float*)d_in[4];
  const float* b2 = (const float*)d_in[5];
  float* out = (float*)d_out;
  char* ws = (char*)d_ws;

  u16* xb = (u16*)(ws + 0);                       // 8 MB
  u16* wt = (u16*)(ws + 8388608);                 // 64 MB (w1t, then w2t)
  u16* h  = (u16*)(ws + 75497472);                // 64 MB
  char* meta = ws + 142606336;
  int*   eos      = (int*)(meta);
  int*   tok_of_g = (int*)(meta + 32768);
  float* wos      = (float*)(meta + 65536);
  float* w_of_g   = (float*)(meta + 98304);
  int*   goff     = (int*)(meta + 131072);
  int*   tiles    = (int*)(meta + 131200);
  int*   ntiles   = (int*)(meta + 131584);

  hipMemsetAsync(out, 0, (size_t)NTOK * DM * 4, stream);

  cvt_x_kernel<<<NTOK * DM / 8 / 256, 256, 0, stream>>>(x, xb);
  transpose_kernel<DM, DH><<<dim3(DH / 64, DM / 64, NE), 256, 0, stream>>>(w1, wt);
  router_kernel<<<NTOK / 4, 256, 0, stream>>>(x, gw, eos, wos);
  build_groups_kernel<<<1, 256, 0, stream>>>(eos, wos, goff, tok_of_g, w_of_g, tiles, ntiles);
  // GEMM1: 1D grid; XCD-chunk + 4x4 supertile remap inside kernel
  moe_gemm<DM, DH, 0, 1><<<TMAX * (DH / 128), 256, 0, stream>>>(
      xb, wt, b1, goff, tok_of_g, w_of_g, tiles, ntiles, h, nullptr);
  transpose_kernel<DH, DM><<<dim3(DM / 64, DH / 64, NE), 256, 0, stream>>>(w2, wt);
  // GEMM2: split-K x2, same remap
  moe_gemm<DH, DM, 1, 2><<<TMAX * (DM / 128) * 2, 256, 0, stream>>>(
      h, wt, b2, goff, tok_of_g, w_of_g, tiles, ntiles, nullptr, out);
}